// Round 11
// baseline (70.264 us; speedup 1.0000x reference)
//
#include <hip/hip_runtime.h>

#define D_MODEL 768
#define BN 64
#define LN_EPS 1e-5f
#define MFMA __builtin_amdgcn_mfma_f32_16x16x32_bf16

typedef __attribute__((ext_vector_type(8))) short bf16x8;
typedef __attribute__((ext_vector_type(4))) float f32x4;

static __device__ __forceinline__ unsigned short f2bf(float f) {
    unsigned int u = __float_as_uint(f);
    u = (u + 0x7FFFu + ((u >> 16) & 1u)) >> 16;
    return (unsigned short)u;
}
static __device__ __forceinline__ float bf2f(unsigned short u) {
    return __uint_as_float(((unsigned int)u) << 16);
}

// prep: fold LN affine into wd; re-layout both weight mats fragment-linear
// (main-kernel weight loads become base + lane*16B = contiguous 1KB/instr).
__global__ void prep(const float* __restrict__ wd, const float* __restrict__ ln_w,
                     const float* __restrict__ ln_b, const float* __restrict__ b_down,
                     const float* __restrict__ wu,
                     unsigned short* __restrict__ wd2_frag, unsigned short* __restrict__ wu_frag,
                     float* __restrict__ S, float* __restrict__ bd2) {
    const int b = blockIdx.x;    // 0..63
    const int t = threadIdx.x;   // 0..63
    const int c = b;
    const int wv = c >> 4, cl = c & 15;
    float s = 0.f, sb = 0.f;
    #pragma unroll
    for (int i = 0; i < 12; ++i) {
        const int d = t + 64 * i;
        const float w0 = wd[c * D_MODEL + d];
        const float w2 = w0 * ln_w[d];
        s  += w2;
        sb += w0 * ln_b[d];
        const int ks = d >> 5, kg = (d >> 3) & 3, e = d & 7;
        wd2_frag[(((wv * 24 + ks) * 64) + kg * 16 + cl) * 8 + e] = f2bf(w2);
    }
    #pragma unroll
    for (int off = 1; off < 64; off <<= 1) {
        s  += __shfl_xor(s, off);
        sb += __shfl_xor(sb, off);
    }
    if (t == 0) { S[c] = s; bd2[c] = b_down[c] + sb; }
    #pragma unroll
    for (int i = 0; i < 12; ++i) {
        const int n = b * 12 + i;
        const float v = wu[n * BN + t];
        const int jj = n >> 4, nl = n & 15;
        const int h = t >> 5, kg = (t >> 3) & 3, e = t & 7;
        wu_frag[(((jj * 2 + h) * 64) + kg * 16 + nl) * 8 + e] = f2bf(v);
    }
}

// R10 structure, but phase-4 residual comes from registers (no x re-read),
// and LDS trimmed to 27264 B so 6 blocks/CU fit.
__global__ __launch_bounds__(256, 6) void adapter_kernel(
    const float* __restrict__ x,
    const unsigned short* __restrict__ wd2_frag, const float* __restrict__ S,
    const float* __restrict__ bd2,
    const unsigned short* __restrict__ wu_frag, const float* __restrict__ b_up,
    float* __restrict__ out)
{
    // sBuf dual-use:
    //   phase 1-2: sX  = bf16 x tile, row stride 768 sh (byte 1536), XOR ((r&15)<<4)
    //   phase 3-4: sOut = bf16 up-tile, row stride 776 sh (byte 1552), linear
    __shared__ __align__(16) unsigned short sBuf[16 * 776];   // 24832 B
    __shared__ __align__(16) unsigned short sDown[16][72];    // 2304 B
    __shared__ float sMu[16], sRs[16];                        // 128 B -> total 27264

    const int tid  = threadIdx.x;
    const int lane = tid & 63;
    const int w    = tid >> 6;       // wave 0..3
    const int kg   = lane >> 4;
    const int l16  = lane & 15;
    const size_t gt0 = (size_t)blockIdx.x * 16;

    ushort4 xb[12];   // this lane's bf16 x values (rows w*4..w*4+3) for phase 4

    // ---------- Phase 1: wave-contiguous x pass (wave owns rows w*4..w*4+3) ----------
    {
        float4 v[12];
        const float* base0 = x + (gt0 + (size_t)(w * 4)) * D_MODEL + lane * 4;
        #pragma unroll
        for (int p = 0; p < 4; ++p)
            #pragma unroll
            for (int sg = 0; sg < 3; ++sg)
                v[p * 3 + sg] = *(const float4*)(base0 + p * D_MODEL + sg * 256);
        #pragma unroll
        for (int p = 0; p < 4; ++p) {
            const int r = w * 4 + p;
            float sum = 0.f, sq = 0.f;
            #pragma unroll
            for (int sg = 0; sg < 3; ++sg) {
                const float4 f = v[p * 3 + sg];
                sum += (f.x + f.y) + (f.z + f.w);
                sq  += (f.x * f.x + f.y * f.y) + (f.z * f.z + f.w * f.w);
            }
            #pragma unroll
            for (int off = 1; off < 64; off <<= 1) {
                sum += __shfl_xor(sum, off);
                sq  += __shfl_xor(sq, off);
            }
            if (lane == 0) {
                const float mu = sum * (1.f / D_MODEL);
                sMu[r] = mu;
                sRs[r] = rsqrtf(sq * (1.f / D_MODEL) - mu * mu + LN_EPS);
            }
            #pragma unroll
            for (int sg = 0; sg < 3; ++sg) {
                const float4 f = v[p * 3 + sg];
                ushort4 o;
                o.x = f2bf(f.x); o.y = f2bf(f.y); o.z = f2bf(f.z); o.w = f2bf(f.w);
                xb[p * 3 + sg] = o;                       // keep for phase-4 residual
                const int bytecol = ((sg * 256 + lane * 4) * 2) ^ ((r & 15) << 4);
                *(ushort4*)((char*)sBuf + r * 1536 + bytecol) = o;
            }
        }
    }
    __syncthreads();

    // ---------- Phase 2: GEMM1, fragment-linear weights (contiguous 1KB loads) ----------
    {
        const int c = w * 16 + l16;
        const unsigned short* bp = wd2_frag + ((size_t)(w * 24) * 64 + lane) * 8;
        const char* sxrow = (const char*)sBuf + l16 * 1536;
        f32x4 acc = {0.f, 0.f, 0.f, 0.f};
        #pragma unroll
        for (int ks = 0; ks < 24; ++ks) {
            const bf16x8 a = *(const bf16x8*)(sxrow + ((ks * 64 + kg * 16) ^ (l16 << 4)));
            const bf16x8 b = *(const bf16x8*)(bp + ks * 512);
            acc = MFMA(a, b, acc, 0, 0, 0);
        }
        const float Sc = S[c], bd = bd2[c];
        #pragma unroll
        for (int r = 0; r < 4; ++r) {
            const int t = kg * 4 + r;
            const float vv = sRs[t] * (acc[r] - sMu[t] * Sc) + bd;
            sDown[t][c] = f2bf(vv > 0.f ? vv : 0.f);
        }
    }
    __syncthreads();   // all sX reads done -> sBuf reusable as sOut

    // ---------- Phase 3: GEMM2 swapped MAC; stage up+b_up (bf16) to sOut ----------
    {
        const bf16x8 pb0 = *(const bf16x8*)&sDown[l16][kg * 8];
        const bf16x8 pb1 = *(const bf16x8*)&sDown[l16][32 + kg * 8];
        #pragma unroll 4
        for (int j = 0; j < 12; ++j) {
            const int jj = 4 * j + w;
            const unsigned short* ap = wu_frag + ((size_t)(jj * 2) * 64 + lane) * 8;
            const bf16x8 a0 = *(const bf16x8*)ap;
            const bf16x8 a1 = *(const bf16x8*)(ap + 512);
            f32x4 acc = {0.f, 0.f, 0.f, 0.f};
            acc = MFMA(a0, pb0, acc, 0, 0, 0);
            acc = MFMA(a1, pb1, acc, 0, 0, 0);
            const int oc = jj * 16 + kg * 4;
            const float4 bu = *(const float4*)(b_up + oc);
            ushort4 o;
            o.x = f2bf(acc[0] + bu.x);
            o.y = f2bf(acc[1] + bu.y);
            o.z = f2bf(acc[2] + bu.z);
            o.w = f2bf(acc[3] + bu.w);
            *(ushort4*)((char*)sBuf + l16 * 1552 + oc * 2) = o;   // row l16, cols oc..oc+3
        }
    }
    __syncthreads();

    // ---------- Phase 4: contiguous stores; residual from registers ----------
    {
        float* orow0 = out + (gt0 + (size_t)(w * 4)) * D_MODEL + lane * 4;
        #pragma unroll
        for (int p = 0; p < 4; ++p) {
            const int r = w * 4 + p;
            #pragma unroll
            for (int sg = 0; sg < 3; ++sg) {
                const ushort4 ub = *(const ushort4*)((char*)sBuf + r * 1552 + (sg * 256 + lane * 4) * 2);
                const ushort4 xv = xb[p * 3 + sg];
                float4 o;
                o.x = bf2f(xv.x) + bf2f(ub.x);
                o.y = bf2f(xv.y) + bf2f(ub.y);
                o.z = bf2f(xv.z) + bf2f(ub.z);
                o.w = bf2f(xv.w) + bf2f(ub.w);
                *(float4*)(orow0 + p * D_MODEL + sg * 256) = o;
            }
        }
    }
}

extern "C" void kernel_launch(void* const* d_in, const int* in_sizes, int n_in,
                              void* d_out, int out_size, void* d_ws, size_t ws_size,
                              hipStream_t stream) {
    const float* x      = (const float*)d_in[0];
    const float* ln_w   = (const float*)d_in[1];
    const float* ln_b   = (const float*)d_in[2];
    const float* w_down = (const float*)d_in[3];
    const float* b_down = (const float*)d_in[4];
    const float* w_up   = (const float*)d_in[5];
    const float* b_up   = (const float*)d_in[6];
    float* out = (float*)d_out;

    unsigned short* wd2_frag = (unsigned short*)d_ws;            // 64*768 ush
    unsigned short* wu_frag  = wd2_frag + BN * D_MODEL;          // 768*64 ush
    float* S   = (float*)((char*)d_ws + 2 * BN * D_MODEL * sizeof(unsigned short));
    float* bd2 = S + BN;

    prep<<<BN, 64, 0, stream>>>(w_down, ln_w, ln_b, b_down, w_up, wd2_frag, wu_frag, S, bd2);

    const int tokens = in_sizes[0] / D_MODEL;   // 32768
    const int grid = tokens / 16;               // 2048 blocks of 16 tokens
    adapter_kernel<<<grid, 256, 0, stream>>>(x, wd2_frag, S, bd2, wu_frag, b_up, out);
}

// Round 12
// 49.879 us; speedup vs baseline: 1.4087x; 1.4087x over previous
//
#include <hip/hip_runtime.h>

#define D_MODEL 768
#define BN 64
#define LN_EPS 1e-5f
#define MFMA __builtin_amdgcn_mfma_f32_16x16x32_bf16

typedef __attribute__((ext_vector_type(8))) short bf16x8;
typedef __attribute__((ext_vector_type(4))) float f32x4;

static __device__ __forceinline__ unsigned short f2bf(float f) {
    unsigned int u = __float_as_uint(f);
    u = (u + 0x7FFFu + ((u >> 16) & 1u)) >> 16;
    return (unsigned short)u;
}
static __device__ __forceinline__ float bf2f(unsigned short u) {
    return __uint_as_float(((unsigned int)u) << 16);
}

// prep: fold LN affine into wd; re-layout both weight mats fragment-linear
// (main-kernel weight loads become base + lane*16B = contiguous 1KB/instr).
__global__ void prep(const float* __restrict__ wd, const float* __restrict__ ln_w,
                     const float* __restrict__ ln_b, const float* __restrict__ b_down,
                     const float* __restrict__ wu,
                     unsigned short* __restrict__ wd2_frag, unsigned short* __restrict__ wu_frag,
                     float* __restrict__ S, float* __restrict__ bd2) {
    const int b = blockIdx.x;    // 0..63
    const int t = threadIdx.x;   // 0..63
    const int c = b;
    const int wv = c >> 4, cl = c & 15;
    float s = 0.f, sb = 0.f;
    #pragma unroll
    for (int i = 0; i < 12; ++i) {
        const int d = t + 64 * i;
        const float w0 = wd[c * D_MODEL + d];
        const float w2 = w0 * ln_w[d];
        s  += w2;
        sb += w0 * ln_b[d];
        const int ks = d >> 5, kg = (d >> 3) & 3, e = d & 7;
        wd2_frag[(((wv * 24 + ks) * 64) + kg * 16 + cl) * 8 + e] = f2bf(w2);
    }
    #pragma unroll
    for (int off = 1; off < 64; off <<= 1) {
        s  += __shfl_xor(s, off);
        sb += __shfl_xor(sb, off);
    }
    if (t == 0) { S[c] = s; bd2[c] = b_down[c] + sb; }
    #pragma unroll
    for (int i = 0; i < 12; ++i) {
        const int n = b * 12 + i;
        const float v = wu[n * BN + t];
        const int jj = n >> 4, nl = n & 15;
        const int h = t >> 5, kg = (t >> 3) & 3, e = t & 7;
        wu_frag[(((jj * 2 + h) * 64) + kg * 16 + nl) * 8 + e] = f2bf(v);
    }
}

// R6 structure + deep rolling register prefetch of L2-resident weights.
__global__ __launch_bounds__(256, 4) void adapter_kernel(
    const float* __restrict__ x,
    const unsigned short* __restrict__ wd2_frag, const float* __restrict__ S,
    const float* __restrict__ bd2,
    const unsigned short* __restrict__ wu_frag, const float* __restrict__ b_up,
    float* __restrict__ out)
{
    __shared__ __align__(16) unsigned short sX[16 * 768];    // XOR ((r&15)<<4) swizzle
    __shared__ __align__(16) unsigned short sDown[16][72];
    __shared__ float sMu[16], sRs[16];

    const int tid  = threadIdx.x;
    const int lane = tid & 63;
    const int w    = tid >> 6;       // wave 0..3
    const int kg   = lane >> 4;
    const int l16  = lane & 15;
    const size_t gt0 = (size_t)blockIdx.x * 16;

    // hoisted block-constant scalars (overlap with phase 1)
    const int c = w * 16 + l16;
    const float Sc = S[c], bd = bd2[c];

    // ---------- Phase 1: wave-contiguous x pass (wave owns rows w*4..w*4+3) ----------
    const unsigned short* bp = wd2_frag + ((size_t)(w * 24) * 64 + lane) * 8;
    bf16x8 bq[6];
    {
        float4 v[12];
        const float* base0 = x + (gt0 + (size_t)(w * 4)) * D_MODEL + lane * 4;
        #pragma unroll
        for (int p = 0; p < 4; ++p)
            #pragma unroll
            for (int sg = 0; sg < 3; ++sg)
                v[p * 3 + sg] = *(const float4*)(base0 + p * D_MODEL + sg * 256);
        // GEMM1 weight pipeline primed while phase 1 computes
        #pragma unroll
        for (int i = 0; i < 6; ++i) bq[i] = *(const bf16x8*)(bp + i * 512);

        #pragma unroll
        for (int p = 0; p < 4; ++p) {
            const int r = w * 4 + p;
            float sum = 0.f, sq = 0.f;
            #pragma unroll
            for (int sg = 0; sg < 3; ++sg) {
                const float4 f = v[p * 3 + sg];
                sum += (f.x + f.y) + (f.z + f.w);
                sq  += (f.x * f.x + f.y * f.y) + (f.z * f.z + f.w * f.w);
            }
            #pragma unroll
            for (int off = 1; off < 64; off <<= 1) {
                sum += __shfl_xor(sum, off);
                sq  += __shfl_xor(sq, off);
            }
            if (lane == 0) {
                const float mu = sum * (1.f / D_MODEL);
                sMu[r] = mu;
                sRs[r] = rsqrtf(sq * (1.f / D_MODEL) - mu * mu + LN_EPS);
            }
            #pragma unroll
            for (int sg = 0; sg < 3; ++sg) {
                const float4 f = v[p * 3 + sg];
                ushort4 o;
                o.x = f2bf(f.x); o.y = f2bf(f.y); o.z = f2bf(f.z); o.w = f2bf(f.w);
                const int bytecol = ((sg * 256 + lane * 4) * 2) ^ ((r & 15) << 4);
                *(ushort4*)((char*)sX + r * 1536 + bytecol) = o;
            }
        }
    }
    __syncthreads();

    // ---------- Phase 2: GEMM1 with depth-6 weight pipeline ----------
    {
        const char* sxrow = (const char*)sX + l16 * 1536;
        f32x4 acc = {0.f, 0.f, 0.f, 0.f};
        #pragma unroll
        for (int ks = 0; ks < 24; ++ks) {
            const bf16x8 a = *(const bf16x8*)(sxrow + ((ks * 64 + kg * 16) ^ (l16 << 4)));
            const bf16x8 b = bq[ks % 6];
            if (ks + 6 < 24) bq[ks % 6] = *(const bf16x8*)(bp + (ks + 6) * 512);
            acc = MFMA(a, b, acc, 0, 0, 0);
        }
        #pragma unroll
        for (int r = 0; r < 4; ++r) {
            const int t = kg * 4 + r;
            const float vv = sRs[t] * (acc[r] - sMu[t] * Sc) + bd;
            sDown[t][c] = f2bf(vv > 0.f ? vv : 0.f);
        }
    }
    // prime GEMM2 weight pipeline before the barrier (flies during sync + pb reads)
    bf16x8 aq0[3], aq1[3];
    #pragma unroll
    for (int i = 0; i < 3; ++i) {
        const unsigned short* ap = wu_frag + ((size_t)((4 * i + w) * 2) * 64 + lane) * 8;
        aq0[i] = *(const bf16x8*)ap;
        aq1[i] = *(const bf16x8*)(ap + 512);
    }
    __syncthreads();

    // ---------- Phase 3: GEMM2 swapped, depth-3 weight pipeline ----------
    {
        const bf16x8 pb0 = *(const bf16x8*)&sDown[l16][kg * 8];
        const bf16x8 pb1 = *(const bf16x8*)&sDown[l16][32 + kg * 8];
        const size_t rowOff = (gt0 + l16) * D_MODEL;
        const char* sxrow = (const char*)sX + l16 * 1536;
        #pragma unroll
        for (int j = 0; j < 12; ++j) {
            const int jj = 4 * j + w;
            const bf16x8 a0 = aq0[j % 3];
            const bf16x8 a1 = aq1[j % 3];
            if (j + 3 < 12) {
                const unsigned short* ap = wu_frag + ((size_t)((4 * (j + 3) + w) * 2) * 64 + lane) * 8;
                aq0[j % 3] = *(const bf16x8*)ap;
                aq1[j % 3] = *(const bf16x8*)(ap + 512);
            }
            f32x4 acc = {0.f, 0.f, 0.f, 0.f};
            acc = MFMA(a0, pb0, acc, 0, 0, 0);
            acc = MFMA(a1, pb1, acc, 0, 0, 0);
            const int oc = jj * 16 + kg * 4;
            const float4 bu = *(const float4*)(b_up + oc);
            const ushort4 xb = *(const ushort4*)(sxrow + ((oc * 2) ^ (l16 << 4)));
            float4 o;
            o.x = acc[0] + bu.x + bf2f(xb.x);
            o.y = acc[1] + bu.y + bf2f(xb.y);
            o.z = acc[2] + bu.z + bf2f(xb.z);
            o.w = acc[3] + bu.w + bf2f(xb.w);
            *(float4*)(out + rowOff + oc) = o;
        }
    }
}

extern "C" void kernel_launch(void* const* d_in, const int* in_sizes, int n_in,
                              void* d_out, int out_size, void* d_ws, size_t ws_size,
                              hipStream_t stream) {
    const float* x      = (const float*)d_in[0];
    const float* ln_w   = (const float*)d_in[1];
    const float* ln_b   = (const float*)d_in[2];
    const float* w_down = (const float*)d_in[3];
    const float* b_down = (const float*)d_in[4];
    const float* w_up   = (const float*)d_in[5];
    const float* b_up   = (const float*)d_in[6];
    float* out = (float*)d_out;

    unsigned short* wd2_frag = (unsigned short*)d_ws;            // 64*768 ush
    unsigned short* wu_frag  = wd2_frag + BN * D_MODEL;          // 768*64 ush
    float* S   = (float*)((char*)d_ws + 2 * BN * D_MODEL * sizeof(unsigned short));
    float* bd2 = S + BN;

    prep<<<BN, 64, 0, stream>>>(w_down, ln_w, ln_b, b_down, w_up, wd2_frag, wu_frag, S, bd2);

    const int tokens = in_sizes[0] / D_MODEL;   // 32768
    const int grid = tokens / 16;               // 2048 blocks of 16 tokens
    adapter_kernel<<<grid, 256, 0, stream>>>(x, wd2_frag, S, bd2, wu_frag, b_up, out);
}